// Round 1
// baseline (64.091 us; speedup 1.0000x reference)
//
#include <hip/hip_runtime.h>

// Reference returns only losses[-1:] (torch loop overwrites `loss` each
// iteration), so we compute the loss for the LAST anchor only:
//   cp      = cos(batch[a_last], batch[p_last])
//   cn      = mean_m cos(batch[a_last], batch[n_last,m])
//   out[0]  = (cp - cn - 1)^2
// cos(x,y) = (x.y) / (max(|x|,eps) * max(|y|,eps))   (torch CosineSimilarity eps)

#define TRIP_EPS 1e-8f

constexpr int D = 512;   // feature dim
constexpr int M = 64;    // negatives per anchor

__global__ __launch_bounds__(1024)
void triplet_last_kernel(const float* __restrict__ batch,
                         const int*   __restrict__ anchors,
                         const int*   __restrict__ positives,
                         const int*   __restrict__ negatives,
                         float* __restrict__ out,
                         int A)
{
    const int tid  = threadIdx.x;
    const int lane = tid & 63;
    const int wave = tid >> 6;        // 0..15

    const int last = A - 1;

    __shared__ __align__(16) float s_a[D];   // anchor row
    __shared__ float s_dn[M];                // a . n_m
    __shared__ float s_sn[M];                // n_m . n_m
    __shared__ float s_misc[3];              // [0]=a.a  [1]=a.p  [2]=p.p

    const int ai = anchors[last];

    // Stage anchor row in LDS (first 512 threads, coalesced).
    if (tid < D) s_a[tid] = batch[(size_t)ai * D + tid];
    __syncthreads();

    // Each lane owns 8 contiguous elements of the row.
    const float4 a0 = *reinterpret_cast<const float4*>(&s_a[lane * 8]);
    const float4 a1 = *reinterpret_cast<const float4*>(&s_a[lane * 8 + 4]);

    // Wave-cooperative: compute (a . x, x . x) for row `row` of batch.
    auto dot2 = [&](int row, float& ad_out, float& xx_out) {
        const float* p = batch + (size_t)row * D + lane * 8;
        const float4 x0 = *reinterpret_cast<const float4*>(p);
        const float4 x1 = *reinterpret_cast<const float4*>(p + 4);
        float ad = a0.x * x0.x + a0.y * x0.y + a0.z * x0.z + a0.w * x0.w
                 + a1.x * x1.x + a1.y * x1.y + a1.z * x1.z + a1.w * x1.w;
        float xx = x0.x * x0.x + x0.y * x0.y + x0.z * x0.z + x0.w * x0.w
                 + x1.x * x1.x + x1.y * x1.y + x1.z * x1.z + x1.w * x1.w;
        #pragma unroll
        for (int off = 32; off >= 1; off >>= 1) {
            ad += __shfl_xor(ad, off, 64);
            xx += __shfl_xor(xx, off, 64);
        }
        ad_out = ad;
        xx_out = xx;
    };

    // 16 waves x 4 negatives each.
    const int* negrow = negatives + (size_t)last * M;
    #pragma unroll
    for (int k = 0; k < 4; ++k) {
        const int m  = wave * 4 + k;
        const int ni = negrow[m];
        float ad, xx;
        dot2(ni, ad, xx);
        if (lane == 0) { s_dn[m] = ad; s_sn[m] = xx; }
    }

    if (wave == 0) {
        // a . a  (== xx of the anchor row)
        float ad, xx;
        dot2(ai, ad, xx);
        if (lane == 0) s_misc[0] = xx;
    } else if (wave == 1) {
        const int pi = positives[last];
        float ad, xx;
        dot2(pi, ad, xx);
        if (lane == 0) { s_misc[1] = ad; s_misc[2] = xx; }
    }
    __syncthreads();

    // Wave 0: lane m computes cos for negative m, reduce, combine, write.
    if (wave == 0) {
        const float na = fmaxf(sqrtf(s_misc[0]), TRIP_EPS);
        const float nn = fmaxf(sqrtf(s_sn[lane]), TRIP_EPS);
        float c = s_dn[lane] / (na * nn);
        #pragma unroll
        for (int off = 32; off >= 1; off >>= 1)
            c += __shfl_xor(c, off, 64);
        if (lane == 0) {
            const float cn = c * (1.0f / (float)M);
            const float np = fmaxf(sqrtf(s_misc[2]), TRIP_EPS);
            const float cp = s_misc[1] / (na * np);
            const float l  = cp - cn - 1.0f;
            out[0] = l * l;
        }
    }
}

extern "C" void kernel_launch(void* const* d_in, const int* in_sizes, int n_in,
                              void* d_out, int out_size, void* d_ws, size_t ws_size,
                              hipStream_t stream)
{
    const float* batch     = (const float*)d_in[0];
    const int*   anchors   = (const int*)d_in[1];
    const int*   positives = (const int*)d_in[2];
    const int*   negatives = (const int*)d_in[3];
    float*       out       = (float*)d_out;

    const int A = in_sizes[1];   // number of anchors (2048)

    triplet_last_kernel<<<1, 1024, 0, stream>>>(batch, anchors, positives,
                                                negatives, out, A);
}

// Round 2
// 62.056 us; speedup vs baseline: 1.0328x; 1.0328x over previous
//
#include <hip/hip_runtime.h>

// Reference returns only losses[-1:] (the torch loop overwrites `loss` each
// iteration), so we compute the loss for the LAST anchor only:
//   cp      = cos(batch[a_last], batch[p_last])
//   cn      = mean_m cos(batch[a_last], batch[n_last,m])
//   out[0]  = (cp - cn - 1)^2
// cos(x,y) = (x.y) / (max(|x|,eps) * max(|y|,eps))   (torch CosineSimilarity eps)
//
// Structure: one block, 16 waves. Wave w computes the 4 dot-products for
// negatives 4w..4w+3; wave 0 also computes |a|^2, wave 1 computes a.p and
// |p|^2. No LDS staging of the anchor row: every wave loads the anchor
// fragments directly (same 2 KB row -> L1 broadcast after first miss), which
// removes the front barrier and keeps the dependency depth at two HBM round
// trips (index -> row), all chains concurrent.

#define TRIP_EPS 1e-8f

constexpr int D = 512;   // feature dim
constexpr int M = 64;    // negatives per anchor

__global__ __launch_bounds__(1024)
void triplet_last_kernel(const float* __restrict__ batch,
                         const int*   __restrict__ anchors,
                         const int*   __restrict__ positives,
                         const int*   __restrict__ negatives,
                         float* __restrict__ out,
                         int A)
{
    const int tid  = threadIdx.x;
    const int lane = tid & 63;
    const int wave = tid >> 6;        // 0..15

    const int last = A - 1;

    __shared__ float s_dn[M];                // a . n_m
    __shared__ float s_sn[M];                // n_m . n_m
    __shared__ float s_misc[3];              // [0]=a.a  [1]=a.p  [2]=p.p

    // Index loads (independent chains, all issued up front).
    const int ai = anchors[last];
    const int* negrow = negatives + (size_t)last * M;
    int ni[4];
    #pragma unroll
    for (int k = 0; k < 4; ++k) ni[k] = negrow[wave * 4 + k];

    // Anchor fragments: each lane owns 8 contiguous floats of the row.
    const float* arow = batch + (size_t)ai * D + lane * 8;
    const float4 a0 = *reinterpret_cast<const float4*>(arow);
    const float4 a1 = *reinterpret_cast<const float4*>(arow + 4);

    // Wave-cooperative (a.x, x.x) for batch row `row`.
    auto dot2 = [&](int row, float& ad_out, float& xx_out) {
        const float* p = batch + (size_t)row * D + lane * 8;
        const float4 x0 = *reinterpret_cast<const float4*>(p);
        const float4 x1 = *reinterpret_cast<const float4*>(p + 4);
        float ad = a0.x * x0.x + a0.y * x0.y + a0.z * x0.z + a0.w * x0.w
                 + a1.x * x1.x + a1.y * x1.y + a1.z * x1.z + a1.w * x1.w;
        float xx = x0.x * x0.x + x0.y * x0.y + x0.z * x0.z + x0.w * x0.w
                 + x1.x * x1.x + x1.y * x1.y + x1.z * x1.z + x1.w * x1.w;
        #pragma unroll
        for (int off = 32; off >= 1; off >>= 1) {
            ad += __shfl_xor(ad, off, 64);
            xx += __shfl_xor(xx, off, 64);
        }
        ad_out = ad;
        xx_out = xx;
    };

    // 16 waves x 4 negatives each.
    #pragma unroll
    for (int k = 0; k < 4; ++k) {
        float ad, xx;
        dot2(ni[k], ad, xx);
        if (lane == 0) { s_dn[wave * 4 + k] = ad; s_sn[wave * 4 + k] = xx; }
    }

    if (wave == 0) {
        // |a|^2 from the already-loaded fragments (no extra memory traffic).
        float aa = a0.x * a0.x + a0.y * a0.y + a0.z * a0.z + a0.w * a0.w
                 + a1.x * a1.x + a1.y * a1.y + a1.z * a1.z + a1.w * a1.w;
        #pragma unroll
        for (int off = 32; off >= 1; off >>= 1)
            aa += __shfl_xor(aa, off, 64);
        if (lane == 0) s_misc[0] = aa;
    } else if (wave == 1) {
        const int pi = positives[last];
        float ap, pp;
        dot2(pi, ap, pp);
        if (lane == 0) { s_misc[1] = ap; s_misc[2] = pp; }
    }
    __syncthreads();

    // Wave 0: lane m holds negative m's terms; reduce, combine, write.
    if (wave == 0) {
        const float na = fmaxf(sqrtf(s_misc[0]), TRIP_EPS);
        const float nn = fmaxf(sqrtf(s_sn[lane]), TRIP_EPS);
        float c = s_dn[lane] / (na * nn);
        #pragma unroll
        for (int off = 32; off >= 1; off >>= 1)
            c += __shfl_xor(c, off, 64);
        if (lane == 0) {
            const float cn = c * (1.0f / (float)M);
            const float np = fmaxf(sqrtf(s_misc[2]), TRIP_EPS);
            const float cp = s_misc[1] / (na * np);
            const float l  = cp - cn - 1.0f;
            out[0] = l * l;
        }
    }
}

extern "C" void kernel_launch(void* const* d_in, const int* in_sizes, int n_in,
                              void* d_out, int out_size, void* d_ws, size_t ws_size,
                              hipStream_t stream)
{
    const float* batch     = (const float*)d_in[0];
    const int*   anchors   = (const int*)d_in[1];
    const int*   positives = (const int*)d_in[2];
    const int*   negatives = (const int*)d_in[3];
    float*       out       = (float*)d_out;

    const int A = in_sizes[1];   // number of anchors (2048)

    triplet_last_kernel<<<1, 1024, 0, stream>>>(batch, anchors, positives,
                                                negatives, out, A);
}